// Round 4
// baseline (179.904 us; speedup 1.0000x reference)
//
#include <hip/hip_runtime.h>

// BaseAttention: B=2 H=16 S=2048 D=64, fp32 in/out.
// Round 10 (resubmit #2 after GPU-acquisition timeout; never measured).
// Barrier-free register-streamed main loop.
//   Round-9 post-mortem: occupancy doubled (18->35.5) but time rose 75.5->81.5us.
//   6100 cyc/iter vs ~1K cyc of work => per-tile __syncthreads + vmcnt(0) drain
//   serializes every tile. K/V per head = 590 KB = L2-resident => LDS staging is
//   pure overhead (common-mistake #7). Fix: prepack K/V images in exact per-lane
//   MFMA fragment order; main loop streams fragments global->VGPR with K
//   double-buffered 1 tile ahead, V+mask single-buffered, ZERO barriers in loop.
//   l computed via v_dot2_f32_f16 on masked packed P (replaces ones-A MFMA:
//   -2 MFMA/iter, -20 VGPR). Cross-wave (key-half) reduction via small LDS at
//   the end only. Preps vectorized (prep_mask int4; prep_kv frag-order images).
//   Carried: Q pre-scaled by 0.125*log2e; mask as u32 AND-words; P packed f16
//   via v_cvt_pkrtz; PV = mfma_f32_32x32x16_f16; no split-K across blocks.

#define S_LEN 2048
#define D_DIM 64
#define N_KT 32
#define NBH 32
#define FRAG_SHORTS 4096               // per-tile frag image: 8 KB (K and V each)

typedef __attribute__((ext_vector_type(8))) short bf16x8;
typedef __attribute__((ext_vector_type(16))) float f32x16;
typedef __attribute__((ext_vector_type(2))) __fp16 fp16x2;
typedef unsigned int u32;
typedef unsigned long long u64;

#define C1 0.180336880111121f    // 0.125 * log2(e)
#define CM (-14426.9504088896f)  // -10000 * log2(e)  (fallback kernel only)

static __device__ __forceinline__ unsigned short f2bf(float f) {
  union { float f; unsigned u; } x; x.f = f;
  return (unsigned short)((x.u + 0x8000u) >> 16);
}
static __device__ __forceinline__ unsigned packbf(float lo, float hi) {
  union { float f; unsigned u; } a, b; a.f = lo; b.f = hi;
  return ((a.u + 0x8000u) >> 16) | ((b.u + 0x8000u) & 0xffff0000u);
}
static __device__ __forceinline__ f32x16 zero16() {
  f32x16 z;
#pragma unroll
  for (int i = 0; i < 16; ++i) z[i] = 0.f;
  return z;
}
static __device__ __forceinline__ unsigned pkh(float lo, float hi) {
  union { fp16x2 h; unsigned u; } x;
  x.h = __builtin_amdgcn_cvt_pkrtz(lo, hi);
  return x.u;
}

// ---- pre-pass: K,V -> per-lane fragment-ordered images (f16/bf16) ----
// K frag image per (bh,kt): [kh(2)][ks(4)][hl(2)][col(32)][8 shorts]
//   element = bf16( K[key = kh*32+col][d = ks*16+hl*8+j] )
// V frag image per (bh,kt): [kcHi(4)][hl(2)][b(2)][col(32)][8 shorts]
//   element = f16( V[key = (2*kcHi+hl)*8+j][d = b*32+col] )
__global__ __launch_bounds__(256) void prep_kv(
    const float* __restrict__ k, const float* __restrict__ v,
    unsigned short* __restrict__ kws, unsigned short* __restrict__ vws) {
  const int kt = blockIdx.x, bh = blockIdx.y;
  const int t = threadIdx.x;
  __shared__ unsigned short Kr[64 * 72];
  __shared__ unsigned short Vr[64 * 72];
  const size_t goff = (size_t)bh * (S_LEN * D_DIM) + (size_t)kt * 64 * D_DIM;
  const float4* kg = (const float4*)(k + goff);
  const float4* vg = (const float4*)(v + goff);
  // phase 1: coalesced load + convert into raw [row][d] LDS tiles (pitch 72)
#pragma unroll
  for (int j = 0; j < 4; ++j) {
    const int i = t + j * 256;
    const int row = i >> 4, c4 = i & 15;  // row = key, c4 = d-group (4 floats)
    const float4 x = kg[i];
    ushort4 w;
    w.x = f2bf(x.x); w.y = f2bf(x.y); w.z = f2bf(x.z); w.w = f2bf(x.w);
    *(ushort4*)&Kr[row * 72 + c4 * 4] = w;
    const float4 y = vg[i];
    const unsigned p01 = pkh(y.x, y.y), p23 = pkh(y.z, y.w);
    uint2 vv; vv.x = p01; vv.y = p23;
    *(uint2*)&Vr[row * 72 + c4 * 4] = vv;
  }
  __syncthreads();
  // phase 2a: K frags — 512 chunks of 16B, coalesced writes
  uint4* kimg4 = (uint4*)(kws + (size_t)(bh * N_KT + kt) * FRAG_SHORTS);
  for (int c = t; c < 512; c += 256) {
    const int col = c & 31, hlc = (c >> 5) & 1, ks = (c >> 6) & 3, khc = c >> 8;
    kimg4[c] = *(const uint4*)&Kr[(khc * 32 + col) * 72 + ks * 16 + hlc * 8];
  }
  // phase 2b: V frags (transpose gather from Vr), coalesced writes
  uint4* vimg4 = (uint4*)(vws + (size_t)(bh * N_KT + kt) * FRAG_SHORTS);
  for (int c = t; c < 512; c += 256) {
    const int col = c & 31, b = (c >> 5) & 1, hlc = (c >> 6) & 1, kcHi = c >> 7;
    const int d = b * 32 + col, kk = (2 * kcHi + hlc) * 8;
    union { unsigned short s[8]; uint4 u; } o;
#pragma unroll
    for (int jj = 0; jj < 8; ++jj) o.s[jj] = Vr[(kk + jj) * 72 + d];
    vimg4[c] = o.u;
  }
}

// ---- pre-pass: mask -> u32 AND-words (same layout as validated rounds) ----
// word (row, hl, kt, p=kb*8+g*2+h) masks keys j0=32kb+8g+4hl+2h (+0,+1);
// half = (mask==0) ? 0xFFFF : 0.  int4-vectorized: thread = one key-quad.
__global__ __launch_bounds__(256) void prep_mask(
    const int* __restrict__ mask, u32* __restrict__ mw) {
  const int gt = blockIdx.x * 256 + threadIdx.x;  // 0 .. 2048*512-1
  const int row = gt >> 9;
  const int qi = gt & 511;                        // key-quad within row
  const int4 m = *(const int4*)(mask + (size_t)row * S_LEN + qi * 4);
  const int kt = qi >> 4;
  const int j = (qi << 2) & 63;                   // key within tile
  const int kb = j >> 5, g = (j >> 3) & 3, hl = (j >> 2) & 1;
  u32 w0 = 0, w1 = 0;
  if (m.x == 0) w0 |= 0x0000FFFFu;
  if (m.y == 0) w0 |= 0xFFFF0000u;
  if (m.z == 0) w1 |= 0x0000FFFFu;
  if (m.w == 0) w1 |= 0xFFFF0000u;
  uint2 wv; wv.x = w0; wv.y = w1;
  *(uint2*)&mw[((size_t)(row * 2 + hl) * N_KT + kt) * 16 + kb * 8 + g * 2] = wv;
}

// ---- main: flash attention, barrier-free register streaming ----
__global__ __launch_bounds__(256, 3) void attn_fwd(
    const float* __restrict__ q, const unsigned short* __restrict__ kws,
    const unsigned short* __restrict__ vws, const u32* __restrict__ mw,
    float* __restrict__ out) {
  const int qt = blockIdx.x;  // 0..31 (64 q rows per block)
  const int bh = blockIdx.y;  // 0..31
  const size_t hoff = (size_t)bh * (S_LEN * D_DIM);

  const int t = threadIdx.x;
  const int wave = t >> 6;
  const int lane = t & 63;
  const int col = lane & 31;
  const int hl = lane >> 5;
  const int qh = wave >> 1;  // q half
  const int kh = wave & 1;   // key half of each tile

  const int qg = qt * 64 + qh * 32 + col;

  // Q^T B-fragments, PRE-SCALED by C1: B[k=d][n=q]
  bf16x8 bQ[4];
  {
    const float* qrow = q + hoff + (size_t)qg * D_DIM;
#pragma unroll
    for (int ks = 0; ks < 4; ++ks) {
      const float4 x0 = *(const float4*)(qrow + ks * 16 + hl * 8);
      const float4 x1 = *(const float4*)(qrow + ks * 16 + hl * 8 + 4);
      union { bf16x8 v; unsigned d[4]; } u;
      u.d[0] = packbf(x0.x * C1, x0.y * C1);
      u.d[1] = packbf(x0.z * C1, x0.w * C1);
      u.d[2] = packbf(x1.x * C1, x1.y * C1);
      u.d[3] = packbf(x1.z * C1, x1.w * C1);
      bQ[ks] = u.v;
    }
  }

  f32x16 oT0 = zero16(), oT1 = zero16();
  float lacc = 0.f;
  const uint4* mrow = (const uint4*)(mw + (size_t)(qg * 2 + hl) * N_KT * 16);

  // per-lane fragment stream bases (16B/lane coalesced within each 32-lane half)
  const unsigned short* kL =
      kws + (size_t)bh * N_KT * FRAG_SHORTS + kh * 2048 + hl * 256 + col * 8;
  const unsigned short* vL =
      vws + (size_t)bh * N_KT * FRAG_SHORTS + kh * 2048 + hl * 512 + col * 8;

#define LDK8(kt_, ks_) (*(const bf16x8*)(kL + (size_t)(kt_) * FRAG_SHORTS + (ks_) * 512))
#define LDV8(kt_, ks2_, b_) \
  (*(const bf16x8*)(vL + (size_t)(kt_) * FRAG_SHORTS + (ks2_) * 1024 + (b_) * 256))

#if __has_builtin(__builtin_amdgcn_fdot2)
  const fp16x2 ones2 = {(__fp16)1.0f, (__fp16)1.0f};
#endif

  auto body = [&](bf16x8 k0, bf16x8 k1, bf16x8 k2, bf16x8 k3, int kt) {
    // V + mask issued first; consumed after QK^T+softmax (latency overlap)
    const bf16x8 v00 = LDV8(kt, 0, 0), v01 = LDV8(kt, 0, 1);
    const bf16x8 v10 = LDV8(kt, 1, 0), v11 = LDV8(kt, 1, 1);
    const uint4 mq0 = mrow[kt * 4 + kh * 2 + 0];
    const uint4 mq1 = mrow[kt * 4 + kh * 2 + 1];

    // S^T = K Q^T : 32-key half x K=64 via 4 k-steps (pre-scaled via Q)
    f32x16 sT = zero16();
    sT = __builtin_amdgcn_mfma_f32_32x32x16_bf16(k0, bQ[0], sT, 0, 0, 0);
    sT = __builtin_amdgcn_mfma_f32_32x32x16_bf16(k1, bQ[1], sT, 0, 0, 0);
    sT = __builtin_amdgcn_mfma_f32_32x32x16_bf16(k2, bQ[2], sT, 0, 0, 0);
    sT = __builtin_amdgcn_mfma_f32_32x32x16_bf16(k3, bQ[3], sT, 0, 0, 0);

    const u32 mwv[8] = {mq0.x, mq0.y, mq0.z, mq0.w,
                        mq1.x, mq1.y, mq1.z, mq1.w};
    unsigned pw[8];
#pragma unroll
    for (int g2 = 0; g2 < 4; ++g2) {
      const float e0 = __builtin_amdgcn_exp2f(sT[g2 * 4 + 0]);
      const float e1 = __builtin_amdgcn_exp2f(sT[g2 * 4 + 1]);
      const float e2 = __builtin_amdgcn_exp2f(sT[g2 * 4 + 2]);
      const float e3 = __builtin_amdgcn_exp2f(sT[g2 * 4 + 3]);
#if __has_builtin(__builtin_amdgcn_fdot2)
      const unsigned w0 = pkh(e0, e1) & mwv[g2 * 2 + 0];
      const unsigned w1 = pkh(e2, e3) & mwv[g2 * 2 + 1];
      pw[g2 * 2 + 0] = w0;
      pw[g2 * 2 + 1] = w1;
      union { unsigned u; fp16x2 h; } c0, c1;
      c0.u = w0; c1.u = w1;
      lacc = __builtin_amdgcn_fdot2(c0.h, ones2, lacc, false);
      lacc = __builtin_amdgcn_fdot2(c1.h, ones2, lacc, false);
#else
      const u32 mlo = mwv[g2 * 2 + 0], mhi = mwv[g2 * 2 + 1];
      const float e0m = (mlo & 0xFFFFu) ? e0 : 0.f;
      const float e1m = (mlo >> 16) ? e1 : 0.f;
      const float e2m = (mhi & 0xFFFFu) ? e2 : 0.f;
      const float e3m = (mhi >> 16) ? e3 : 0.f;
      pw[g2 * 2 + 0] = pkh(e0m, e1m);
      pw[g2 * 2 + 1] = pkh(e2m, e3m);
      lacc += (e0m + e1m) + (e2m + e3m);
#endif
    }

    // O^T += Vt * P^T (V frags pre-gathered in exact A-operand order)
#pragma unroll
    for (int ks2 = 0; ks2 < 2; ++ks2) {
      const unsigned d0 = pw[4 * ks2 + 0], d1 = pw[4 * ks2 + 1];
      const unsigned d2 = pw[4 * ks2 + 2], d3 = pw[4 * ks2 + 3];
      const unsigned s0 = hl ? d0 : d2;
      const unsigned s1 = hl ? d1 : d3;
      const unsigned r0 = (unsigned)__shfl_xor((int)s0, 32);
      const unsigned r1 = (unsigned)__shfl_xor((int)s1, 32);
      union { bf16x8 v; unsigned d[4]; } pf;
      pf.d[0] = hl ? r0 : d0;
      pf.d[1] = hl ? r1 : d1;
      pf.d[2] = hl ? d2 : r0;
      pf.d[3] = hl ? d3 : r1;
      const bf16x8 aV0 = ks2 ? v10 : v00;
      const bf16x8 aV1 = ks2 ? v11 : v01;
      oT0 = __builtin_amdgcn_mfma_f32_32x32x16_f16(aV0, pf.v, oT0, 0, 0, 0);
      oT1 = __builtin_amdgcn_mfma_f32_32x32x16_f16(aV1, pf.v, oT1, 0, 0, 0);
    }
  };

  // main loop: K double-buffered one tile ahead, no barriers anywhere
  bf16x8 ka0 = LDK8(0, 0), ka1 = LDK8(0, 1), ka2 = LDK8(0, 2), ka3 = LDK8(0, 3);
  bf16x8 kb0, kb1, kb2, kb3;
  for (int kt = 0; kt < N_KT; kt += 2) {
    kb0 = LDK8(kt + 1, 0); kb1 = LDK8(kt + 1, 1);
    kb2 = LDK8(kt + 1, 2); kb3 = LDK8(kt + 1, 3);
    body(ka0, ka1, ka2, ka3, kt);
    if (kt + 2 < N_KT) {
      ka0 = LDK8(kt + 2, 0); ka1 = LDK8(kt + 2, 1);
      ka2 = LDK8(kt + 2, 2); ka3 = LDK8(kt + 2, 3);
    }
    body(kb0, kb1, kb2, kb3, kt + 1);
  }
#undef LDK8
#undef LDV8

  // ---- cross-wave key-half reduction via small LDS (only sync points) ----
  __shared__ float xb[64 * 68];
  __shared__ float lb[64];
  const float l2 = lacc + __shfl_xor(lacc, 32);  // both hl halves of this kh
  float* xr = xb + (size_t)(qh * 32 + col) * 68;
  if (kh) {
#pragma unroll
    for (int rg = 0; rg < 4; ++rg) {
      float4 w0, w1;
      w0.x = oT0[rg * 4 + 0]; w0.y = oT0[rg * 4 + 1];
      w0.z = oT0[rg * 4 + 2]; w0.w = oT0[rg * 4 + 3];
      w1.x = oT1[rg * 4 + 0]; w1.y = oT1[rg * 4 + 1];
      w1.z = oT1[rg * 4 + 2]; w1.w = oT1[rg * 4 + 3];
      *(float4*)(xr + 8 * rg + 4 * hl) = w0;
      *(float4*)(xr + 32 + 8 * rg + 4 * hl) = w1;
    }
    if (!hl) lb[qh * 32 + col] = l2;
  }
  __syncthreads();
  if (!kh) {
    const float inv = 1.0f / (l2 + lb[qh * 32 + col]);
    float* orow = out + hoff + (size_t)qg * D_DIM;
#pragma unroll
    for (int rg = 0; rg < 4; ++rg) {
      const float4 a0 = *(const float4*)(xr + 8 * rg + 4 * hl);
      const float4 a1 = *(const float4*)(xr + 32 + 8 * rg + 4 * hl);
      float4 w0, w1;
      w0.x = (oT0[rg * 4 + 0] + a0.x) * inv;
      w0.y = (oT0[rg * 4 + 1] + a0.y) * inv;
      w0.z = (oT0[rg * 4 + 2] + a0.z) * inv;
      w0.w = (oT0[rg * 4 + 3] + a0.w) * inv;
      w1.x = (oT1[rg * 4 + 0] + a1.x) * inv;
      w1.y = (oT1[rg * 4 + 1] + a1.y) * inv;
      w1.z = (oT1[rg * 4 + 2] + a1.z) * inv;
      w1.w = (oT1[rg * 4 + 3] + a1.w) * inv;
      *(float4*)(orow + 8 * rg + 4 * hl) = w0;
      *(float4*)(orow + 32 + 8 * rg + 4 * hl) = w1;
    }
  }
}

// ---- fallback (round-4 kernel, self-staging) if ws is too small ----
#define LDK 72
#define LDV 72
__global__ __launch_bounds__(256, 2) void attn_fwd_self(
    const float* __restrict__ q, const float* __restrict__ k,
    const float* __restrict__ v, const int* __restrict__ mask,
    float* __restrict__ out) {
  const int qt = blockIdx.x;
  const int bh = blockIdx.y;
  const size_t hoff = (size_t)bh * (S_LEN * D_DIM);
  __shared__ unsigned short Ks[64 * LDK];
  __shared__ unsigned short Vt[64 * LDV];
  const int t = threadIdx.x;
  const int wave = t >> 6;
  const int lane = t & 63;
  const int col = lane & 31;
  const int hl = lane >> 5;
  const int sw = col >> 2;
  const int qg = qt * 128 + wave * 32 + col;
  bf16x8 bQ[4];
  {
    const float* qrow = q + hoff + (size_t)qg * D_DIM;
#pragma unroll
    for (int ks = 0; ks < 4; ++ks) {
      const float4 x0 = *(const float4*)(qrow + ks * 16 + hl * 8);
      const float4 x1 = *(const float4*)(qrow + ks * 16 + hl * 8 + 4);
      union { bf16x8 v; unsigned d[4]; } u;
      u.d[0] = packbf(x0.x, x0.y);
      u.d[1] = packbf(x0.z, x0.w);
      u.d[2] = packbf(x1.x, x1.y);
      u.d[3] = packbf(x1.z, x1.w);
      bQ[ks] = u.v;
    }
  }
  float4 pk[4], pv[4];
  {
    const float4* kg = (const float4*)(k + hoff);
    const float4* vg = (const float4*)(v + hoff);
#pragma unroll
    for (int j = 0; j < 4; ++j) { pk[j] = kg[t + j * 256]; pv[j] = vg[t + j * 256]; }
  }
  f32x16 oT0 = zero16(), oT1 = zero16();
  float lacc = 0.f;
  const int* mrow = mask + (size_t)qg * S_LEN;
  for (int kt = 0; kt < N_KT; ++kt) {
    __syncthreads();
#pragma unroll
    for (int j = 0; j < 4; ++j) {
      const int i = t + j * 256;
      const int row = i >> 4, c4 = i & 15;
      ushort4 w;
      w.x = f2bf(pk[j].x); w.y = f2bf(pk[j].y);
      w.z = f2bf(pk[j].z); w.w = f2bf(pk[j].w);
      *(ushort4*)&Ks[row * LDK + c4 * 4] = w;
      const int swc = 8 * (((row >> 3) + c4) & 7) + (row & 7);
      Vt[(4 * c4 + 0) * LDV + swc] = f2bf(pv[j].x);
      Vt[(4 * c4 + 1) * LDV + swc] = f2bf(pv[j].y);
      Vt[(4 * c4 + 2) * LDV + swc] = f2bf(pv[j].z);
      Vt[(4 * c4 + 3) * LDV + swc] = f2bf(pv[j].w);
    }
    __syncthreads();
    if (kt + 1 < N_KT) {
      const float4* kg = (const float4*)(k + hoff + (size_t)(kt + 1) * 64 * D_DIM);
      const float4* vg = (const float4*)(v + hoff + (size_t)(kt + 1) * 64 * D_DIM);
#pragma unroll
      for (int j = 0; j < 4; ++j) { pk[j] = kg[t + j * 256]; pv[j] = vg[t + j * 256]; }
    }
    int4 mq[2][4];
#pragma unroll
    for (int kb = 0; kb < 2; ++kb)
#pragma unroll
      for (int g = 0; g < 4; ++g)
        mq[kb][g] = *(const int4*)(mrow + kt * 64 + kb * 32 + g * 8 + hl * 4);
    f32x16 sT0 = zero16(), sT1 = zero16();
#pragma unroll
    for (int ks = 0; ks < 4; ++ks) {
      const bf16x8 aK0 = *(const bf16x8*)&Ks[col * LDK + ks * 16 + hl * 8];
      const bf16x8 aK1 = *(const bf16x8*)&Ks[(32 + col) * LDK + ks * 16 + hl * 8];
      sT0 = __builtin_amdgcn_mfma_f32_32x32x16_bf16(aK0, bQ[ks], sT0, 0, 0, 0);
      sT1 = __builtin_amdgcn_mfma_f32_32x32x16_bf16(aK1, bQ[ks], sT1, 0, 0, 0);
    }
    unsigned pw[2][8];
#pragma unroll
    for (int kb = 0; kb < 2; ++kb) {
      const f32x16 sT = kb ? sT1 : sT0;
      float e[16];
#pragma unroll
      for (int g = 0; g < 4; ++g) {
        const int4 mv = mq[kb][g];
        const int* mvp = &mv.x;
#pragma unroll
        for (int r3 = 0; r3 < 4; ++r3) {
          const int reg = g * 4 + r3;
          const float bias = mvp[r3] ? CM : 0.0f;
          const float ev = __builtin_amdgcn_exp2f(fmaf(sT[reg], C1, bias));
          e[reg] = ev;
          lacc += ev;
        }
        pw[kb][g * 2 + 0] = packbf(e[g * 4 + 0], e[g * 4 + 1]);
        pw[kb][g * 2 + 1] = packbf(e[g * 4 + 2], e[g * 4 + 3]);
      }
    }
#pragma unroll
    for (int ks = 0; ks < 4; ++ks) {
      const int kb = ks >> 1, h = ks & 1;
      const unsigned d0 = pw[kb][4 * h + 0], d1 = pw[kb][4 * h + 1];
      const unsigned d2 = pw[kb][4 * h + 2], d3 = pw[kb][4 * h + 3];
      const unsigned s0 = hl ? d0 : d2;
      const unsigned s1 = hl ? d1 : d3;
      const unsigned r0 = (unsigned)__shfl_xor((int)s0, 32);
      const unsigned r1 = (unsigned)__shfl_xor((int)s1, 32);
      union { bf16x8 v; unsigned d[4]; } pf;
      pf.d[0] = hl ? r0 : d0;
      pf.d[1] = hl ? r1 : d1;
      pf.d[2] = hl ? d2 : r0;
      pf.d[3] = hl ? d3 : r1;
      const int cpr = 8 * (((2 * ks + hl) + sw) & 7);
      const bf16x8 aV0 = *(const bf16x8*)&Vt[col * LDV + cpr];
      const bf16x8 aV1 = *(const bf16x8*)&Vt[(32 + col) * LDV + cpr];
      oT0 = __builtin_amdgcn_mfma_f32_32x32x16_bf16(aV0, pf.v, oT0, 0, 0, 0);
      oT1 = __builtin_amdgcn_mfma_f32_32x32x16_bf16(aV1, pf.v, oT1, 0, 0, 0);
    }
  }
  const float ltot = lacc + __shfl_xor(lacc, 32);
  const float inv = 1.0f / ltot;
  float* orow = out + hoff + (size_t)qg * D_DIM;
#pragma unroll
  for (int rg = 0; rg < 4; ++rg) {
    float4 w0, w1;
    w0.x = oT0[rg * 4 + 0] * inv; w0.y = oT0[rg * 4 + 1] * inv;
    w0.z = oT0[rg * 4 + 2] * inv; w0.w = oT0[rg * 4 + 3] * inv;
    w1.x = oT1[rg * 4 + 0] * inv; w1.y = oT1[rg * 4 + 1] * inv;
    w1.z = oT1[rg * 4 + 2] * inv; w1.w = oT1[rg * 4 + 3] * inv;
    *(float4*)(orow + 8 * rg + 4 * hl) = w0;
    *(float4*)(orow + 32 + 8 * rg + 4 * hl) = w1;
  }
}

extern "C" void kernel_launch(void* const* d_in, const int* in_sizes, int n_in,
                              void* d_out, int out_size, void* d_ws, size_t ws_size,
                              hipStream_t stream) {
  const float* q = (const float*)d_in[0];
  const float* k = (const float*)d_in[1];
  const float* v = (const float*)d_in[2];
  const int* mask = (const int*)d_in[3];
  float* out = (float*)d_out;

  const size_t img_shorts = (size_t)NBH * N_KT * FRAG_SHORTS;     // per image
  const size_t mw_words = (size_t)S_LEN * 2 * N_KT * 16;          // u32 count
  const size_t need = img_shorts * 2 * sizeof(unsigned short) + mw_words * 4;

  if (ws_size >= need) {
    unsigned short* kws = (unsigned short*)d_ws;
    unsigned short* vws = kws + img_shorts;
    u32* mwp = (u32*)(vws + img_shorts);
    prep_kv<<<dim3(N_KT, NBH), dim3(256), 0, stream>>>(k, v, kws, vws);
    prep_mask<<<dim3((S_LEN * (S_LEN / 4)) / 256), dim3(256), 0, stream>>>(mask, mwp);
    attn_fwd<<<dim3(S_LEN / 64, NBH), dim3(256), 0, stream>>>(q, kws, vws, mwp, out);
  } else {
    attn_fwd_self<<<dim3(S_LEN / 128, NBH), dim3(256), 0, stream>>>(q, k, v, mask, out);
  }
}